// Round 1
// baseline (2226.556 us; speedup 1.0000x reference)
//
#include <hip/hip_runtime.h>
#include <hip/hip_bf16.h>

typedef __attribute__((ext_vector_type(8))) short bf16x8;
typedef __attribute__((ext_vector_type(4))) float f32x4;

#define DEVI __device__ __forceinline__

DEVI unsigned short f2bf_bits(float f) {
    __hip_bfloat16 h = __float2bfloat16(f);
    return *reinterpret_cast<unsigned short*>(&h);
}

// ---------------- patchify: x[B,C,384,384] -> patches bf16 [4608][1536] ----------------
// patch_dim index = (p1*16+p2)*6 + c ; token = gh*24+gw
__global__ __launch_bounds__(256) void patchify_kernel(const float* __restrict__ x,
                                                       unsigned short* __restrict__ patches)
{
    size_t i = (size_t)blockIdx.x * 256 + threadIdx.x;   // 8*6*384*384 = 7,077,888 exactly
    int j = (int)(i % 384);
    size_t t = i / 384;
    int r = (int)(t % 384); t /= 384;
    int c = (int)(t % 6);
    int b = (int)(t / 6);
    int gh = r >> 4, p1 = r & 15, gw = j >> 4, p2 = j & 15;
    int prow = b * 576 + gh * 24 + gw;
    int pcol = (p1 * 16 + p2) * 6 + c;
    patches[(size_t)prow * 1536 + pcol] = f2bf_bits(x[i]);
}

// ---------------- weight convert + transpose: W f32 [K][N] -> Wt bf16 [N][K] ----------------
__global__ __launch_bounds__(256) void convT_kernel(const float* __restrict__ W,
                                                    __hip_bfloat16* __restrict__ Wt,
                                                    int K, int N)
{
    __shared__ float tile[32][33];
    int n0 = blockIdx.x * 32, k0 = blockIdx.y * 32;
    int tx = threadIdx.x & 31, ty = threadIdx.x >> 5;   // ty 0..7
#pragma unroll
    for (int i = 0; i < 4; i++)
        tile[ty + 8 * i][tx] = W[(size_t)(k0 + ty + 8 * i) * N + n0 + tx];
    __syncthreads();
#pragma unroll
    for (int i = 0; i < 4; i++)
        Wt[(size_t)(n0 + ty + 8 * i) * K + k0 + tx] = __float2bfloat16(tile[tx][ty + 8 * i]);
}

// ---------------- layernorm over 768 cols ----------------
DEVI void st_ln(float* p, float v) { *p = v; }
DEVI void st_ln(__hip_bfloat16* p, float v) { *p = __float2bfloat16(v); }

template <typename OutT>
__global__ __launch_bounds__(256) void ln_kernel(const float* __restrict__ x,
                                                 const float* __restrict__ g,
                                                 const float* __restrict__ b,
                                                 OutT* __restrict__ out)
{
    int row = blockIdx.x, tid = threadIdx.x;
    const float* xr = x + (size_t)row * 768;
    float v0 = xr[tid], v1 = xr[tid + 256], v2 = xr[tid + 512];
    float s = v0 + v1 + v2;
    float s2 = v0 * v0 + v1 * v1 + v2 * v2;
#pragma unroll
    for (int m = 32; m >= 1; m >>= 1) { s += __shfl_xor(s, m); s2 += __shfl_xor(s2, m); }
    __shared__ float red[8];
    int w = tid >> 6;
    if ((tid & 63) == 0) { red[w] = s; red[4 + w] = s2; }
    __syncthreads();
    s = red[0] + red[1] + red[2] + red[3];
    s2 = red[4] + red[5] + red[6] + red[7];
    float mean = s * (1.0f / 768.0f);
    float var = s2 * (1.0f / 768.0f) - mean * mean;
    float rstd = rsqrtf(var + 1e-5f);
    OutT* orow = out + (size_t)row * 768;
    st_ln(&orow[tid], (v0 - mean) * rstd * g[tid] + b[tid]);
    st_ln(&orow[tid + 256], (v1 - mean) * rstd * g[tid + 256] + b[tid + 256]);
    st_ln(&orow[tid + 512], (v2 - mean) * rstd * g[tid + 512] + b[tid + 512]);
}

// ---------------- bf16 MFMA GEMM: C[M,N] = A[M,K] @ Bt[N,K]^T (+bias)(+gelu)(+resid) ----------------
// 128x128 tile, BK=32, 4 waves (2x2 of 64x64), mfma_f32_16x16x32_bf16.
// k-slot order is applied identically to A and B fragments -> result invariant to the
// hardware's internal k permutation; only lane structure (row/col=lane&15, grp=lane>>4) assumed.
template <bool BIAS, bool RESID, bool GELU, bool BF16OUT>
__global__ __launch_bounds__(256) void gemm_bt_kernel(
    const __hip_bfloat16* __restrict__ A,
    const __hip_bfloat16* __restrict__ Bt,
    const float* __restrict__ bias,
    const float* __restrict__ resid,
    float* __restrict__ Cf,
    __hip_bfloat16* __restrict__ Cb,
    int M, int N, int K)
{
    constexpr int BK = 32;
    __shared__ __align__(16) __hip_bfloat16 As[128][BK + 4];
    __shared__ __align__(16) __hip_bfloat16 Bs[128][BK + 4];
    const int tid = threadIdx.x;
    const int wid = tid >> 6, lane = tid & 63;
    const int g = lane >> 4, l16 = lane & 15;
    const int wm = (wid >> 1) * 64, wn = (wid & 1) * 64;
    const int bm = blockIdx.y * 128, bn = blockIdx.x * 128;
    const int sr = tid >> 2, scc = (tid & 3) * 8;

    f32x4 acc[4][4] = {};

    for (int k0 = 0; k0 < K; k0 += BK) {
        int4 a0 = *(const int4*)&A[(size_t)(bm + sr) * K + k0 + scc];
        int4 a1 = *(const int4*)&A[(size_t)(bm + sr + 64) * K + k0 + scc];
        int4 b0 = *(const int4*)&Bt[(size_t)(bn + sr) * K + k0 + scc];
        int4 b1 = *(const int4*)&Bt[(size_t)(bn + sr + 64) * K + k0 + scc];
        *(int2*)&As[sr][scc] = make_int2(a0.x, a0.y);
        *(int2*)&As[sr][scc + 4] = make_int2(a0.z, a0.w);
        *(int2*)&As[sr + 64][scc] = make_int2(a1.x, a1.y);
        *(int2*)&As[sr + 64][scc + 4] = make_int2(a1.z, a1.w);
        *(int2*)&Bs[sr][scc] = make_int2(b0.x, b0.y);
        *(int2*)&Bs[sr][scc + 4] = make_int2(b0.z, b0.w);
        *(int2*)&Bs[sr + 64][scc] = make_int2(b1.x, b1.y);
        *(int2*)&Bs[sr + 64][scc + 4] = make_int2(b1.z, b1.w);
        __syncthreads();

        bf16x8 af[4], bfr[4];
#pragma unroll
        for (int mi = 0; mi < 4; mi++) {
            const unsigned short* rp = (const unsigned short*)&As[wm + mi * 16 + l16][0];
            ushort4 lo = *(const ushort4*)&rp[4 * g];
            ushort4 hi = *(const ushort4*)&rp[16 + 4 * g];
            af[mi] = bf16x8{(short)lo.x, (short)lo.y, (short)lo.z, (short)lo.w,
                            (short)hi.x, (short)hi.y, (short)hi.z, (short)hi.w};
        }
#pragma unroll
        for (int ni = 0; ni < 4; ni++) {
            const unsigned short* rp = (const unsigned short*)&Bs[wn + ni * 16 + l16][0];
            ushort4 lo = *(const ushort4*)&rp[4 * g];
            ushort4 hi = *(const ushort4*)&rp[16 + 4 * g];
            bfr[ni] = bf16x8{(short)lo.x, (short)lo.y, (short)lo.z, (short)lo.w,
                             (short)hi.x, (short)hi.y, (short)hi.z, (short)hi.w};
        }
#pragma unroll
        for (int mi = 0; mi < 4; mi++)
#pragma unroll
            for (int ni = 0; ni < 4; ni++)
                acc[mi][ni] = __builtin_amdgcn_mfma_f32_16x16x32_bf16(af[mi], bfr[ni], acc[mi][ni], 0, 0, 0);
        __syncthreads();
    }

#pragma unroll
    for (int mi = 0; mi < 4; mi++) {
#pragma unroll
        for (int ni = 0; ni < 4; ni++) {
            int gcol = bn + wn + ni * 16 + l16;
            float bval = 0.0f;
            if (BIAS) bval = bias[gcol];
#pragma unroll
            for (int r = 0; r < 4; r++) {
                int grow = bm + wm + mi * 16 + 4 * g + r;   // C/D: row=(lane>>4)*4+reg, col=lane&15
                float v = acc[mi][ni][r] + bval;
                if (GELU) v = 0.5f * v * (1.0f + erff(v * 0.70710678118654752f));
                if (RESID) v += resid[(size_t)grow * N + gcol];
                if (BF16OUT) Cb[(size_t)grow * N + gcol] = __float2bfloat16(v);
                else Cf[(size_t)grow * N + gcol] = v;
            }
        }
    }
}

// ---------------- fused attention (fp32): softmax(q@k^T*scale + bias) @ v ----------------
// grid (36 qtiles, 12 heads, 8 batch), block 256. 16 queries/block, full 576-key score rows in LDS.
__global__ __launch_bounds__(256) void attn_kernel(const float* __restrict__ qkv,
                                                   const float* __restrict__ bias,   // [12][576][576] this layer
                                                   unsigned short* __restrict__ o)   // bf16 [4608][768]
{
    const int qt = blockIdx.x, h = blockIdx.y, bb = blockIdx.z;
    const int q0 = qt * 16;
    __shared__ float qs[16][68];
    __shared__ float scs[16][584];
    __shared__ float kv[64][68];
    const int tid = threadIdx.x;

    {   // load Q tile
        int r = tid >> 4, c4 = (tid & 15) * 4;
        *(float4*)&qs[r][c4] = *(const float4*)&qkv[(size_t)(bb * 576 + q0 + r) * 2304 + h * 64 + c4];
    }
    __syncthreads();

    const int qi = tid >> 4;
    const int j0 = tid & 15;
    const float scale = 0.125f;   // 64^-0.5

    // phase 1: scores = q.k*scale + bias
    for (int c0 = 0; c0 < 576; c0 += 64) {
        {
            int r = tid >> 2, cb = (tid & 3) * 16;
            const float* src = &qkv[(size_t)(bb * 576 + c0 + r) * 2304 + 768 + h * 64 + cb];
#pragma unroll
            for (int i = 0; i < 4; i++)
                *(float4*)&kv[r][cb + 4 * i] = *(const float4*)&src[4 * i];
        }
        __syncthreads();
        float d0 = 0, d1 = 0, d2 = 0, d3 = 0;
#pragma unroll 4
        for (int d = 0; d < 64; d += 4) {
            float4 q4 = *(const float4*)&qs[qi][d];
            float4 k0v = *(const float4*)&kv[j0][d];
            float4 k1v = *(const float4*)&kv[j0 + 16][d];
            float4 k2v = *(const float4*)&kv[j0 + 32][d];
            float4 k3v = *(const float4*)&kv[j0 + 48][d];
            d0 += q4.x * k0v.x + q4.y * k0v.y + q4.z * k0v.z + q4.w * k0v.w;
            d1 += q4.x * k1v.x + q4.y * k1v.y + q4.z * k1v.z + q4.w * k1v.w;
            d2 += q4.x * k2v.x + q4.y * k2v.y + q4.z * k2v.z + q4.w * k2v.w;
            d3 += q4.x * k3v.x + q4.y * k3v.y + q4.z * k3v.z + q4.w * k3v.w;
        }
        const float* brow = &bias[((size_t)h * 576 + q0 + qi) * 576 + c0];
        scs[qi][c0 + j0] = d0 * scale + brow[j0];
        scs[qi][c0 + j0 + 16] = d1 * scale + brow[j0 + 16];
        scs[qi][c0 + j0 + 32] = d2 * scale + brow[j0 + 32];
        scs[qi][c0 + j0 + 48] = d3 * scale + brow[j0 + 48];
        __syncthreads();
    }

    // phase 2: row softmax (16 lanes per row, all within one wave's 16-group)
    {
        float mx = -1e30f;
#pragma unroll
        for (int s = 0; s < 36; s++) mx = fmaxf(mx, scs[qi][j0 + 16 * s]);
#pragma unroll
        for (int m = 8; m >= 1; m >>= 1) mx = fmaxf(mx, __shfl_xor(mx, m));
        float sum = 0.0f;
#pragma unroll
        for (int s = 0; s < 36; s++) {
            float e = __expf(scs[qi][j0 + 16 * s] - mx);
            scs[qi][j0 + 16 * s] = e;
            sum += e;
        }
#pragma unroll
        for (int m = 8; m >= 1; m >>= 1) sum += __shfl_xor(sum, m);
        float inv = 1.0f / sum;
#pragma unroll
        for (int s = 0; s < 36; s++) scs[qi][j0 + 16 * s] *= inv;
    }
    __syncthreads();

    // phase 3: attn @ V
    float4 acc = {0, 0, 0, 0};
    const int dg = tid & 15;
    for (int c0 = 0; c0 < 576; c0 += 64) {
        {
            int r = tid >> 2, cb = (tid & 3) * 16;
            const float* src = &qkv[(size_t)(bb * 576 + c0 + r) * 2304 + 1536 + h * 64 + cb];
#pragma unroll
            for (int i = 0; i < 4; i++)
                *(float4*)&kv[r][cb + 4 * i] = *(const float4*)&src[4 * i];
        }
        __syncthreads();
#pragma unroll 4
        for (int j = 0; j < 64; j += 4) {
            float4 p4 = *(const float4*)&scs[qi][c0 + j];
            float4 v0 = *(const float4*)&kv[j][dg * 4];
            float4 v1 = *(const float4*)&kv[j + 1][dg * 4];
            float4 v2 = *(const float4*)&kv[j + 2][dg * 4];
            float4 v3 = *(const float4*)&kv[j + 3][dg * 4];
            acc.x += p4.x * v0.x + p4.y * v1.x + p4.z * v2.x + p4.w * v3.x;
            acc.y += p4.x * v0.y + p4.y * v1.y + p4.z * v2.y + p4.w * v3.y;
            acc.z += p4.x * v0.z + p4.y * v1.z + p4.z * v2.z + p4.w * v3.z;
            acc.w += p4.x * v0.w + p4.y * v1.w + p4.z * v2.w + p4.w * v3.w;
        }
        __syncthreads();
    }
    ushort4 pk;
    pk.x = f2bf_bits(acc.x);
    pk.y = f2bf_bits(acc.y);
    pk.z = f2bf_bits(acc.z);
    pk.w = f2bf_bits(acc.w);
    *(ushort4*)&o[(size_t)(bb * 576 + q0 + qi) * 768 + h * 64 + dg * 4] = pk;
}

// ---------------- mean pool over 576 tokens ----------------
__global__ __launch_bounds__(256) void pool_kernel(const float* __restrict__ tok, float* __restrict__ pooled)
{
    int d = blockIdx.x * 256 + threadIdx.x;   // grid.x = 3
    int b = blockIdx.y;
    float s = 0.0f;
    for (int n = 0; n < 576; n++) s += tok[(size_t)(b * 576 + n) * 768 + d];
    pooled[b * 768 + d] = s * (1.0f / 576.0f);
}

// ---------------- classifier head: out[8][1000] = lnp @ w_head + b_head ----------------
__global__ __launch_bounds__(256) void head_kernel(const float* __restrict__ lnp,
                                                   const float* __restrict__ w,
                                                   const float* __restrict__ bh,
                                                   float* __restrict__ out)
{
    int c = blockIdx.x * 256 + threadIdx.x;
    int b = blockIdx.y;
    if (c >= 1000) return;
    float s = bh[c];
    for (int d = 0; d < 768; d++) s += lnp[b * 768 + d] * w[(size_t)d * 1000 + c];
    out[b * 1000 + c] = s;
}

extern "C" void kernel_launch(void* const* d_in, const int* in_sizes, int n_in,
                              void* d_out, int out_size, void* d_ws, size_t ws_size,
                              hipStream_t stream)
{
    const float* x = (const float*)d_in[0];
    const float* patch_w = (const float*)d_in[1];
    const float* patch_b = (const float*)d_in[2];
    const float* ln1_g = (const float*)d_in[3];
    const float* ln1_b = (const float*)d_in[4];
    const float* w_qkv = (const float*)d_in[5];
    const float* bias_att = (const float*)d_in[6];
    const float* w_out = (const float*)d_in[7];
    const float* ln2_g = (const float*)d_in[8];
    const float* ln2_b = (const float*)d_in[9];
    const float* w1 = (const float*)d_in[10];
    const float* b1 = (const float*)d_in[11];
    const float* w2 = (const float*)d_in[12];
    const float* b2 = (const float*)d_in[13];
    const float* lnh_g = (const float*)d_in[14];
    const float* lnh_b = (const float*)d_in[15];
    const float* w_head = (const float*)d_in[16];
    const float* b_head = (const float*)d_in[17];
    float* out = (float*)d_out;

    char* ws = (char*)d_ws;
    float* tok = (float*)(ws + 0);                               // 4608*768 f32   = 14,155,776 B
    float* qkv = (float*)(ws + 14155776);                        // 4608*2304 f32  = 42,467,328 B
    float* pooled = (float*)(ws + 56623104);                     // 8*768 f32
    float* pooledln = (float*)(ws + 56647680);                   // 8*768 f32
    __hip_bfloat16* patches = (__hip_bfloat16*)(ws + 56672256);  // 4608*1536 bf16 = 14,155,776 B
    __hip_bfloat16* h_bf = (__hip_bfloat16*)(ws + 70828032);     // 4608*768 bf16  =  7,077,888 B
    __hip_bfloat16* o_bf = (__hip_bfloat16*)(ws + 77905920);     // 4608*768 bf16  =  7,077,888 B
    __hip_bfloat16* hid_bf = (__hip_bfloat16*)(ws + 84983808);   // 4608*3072 bf16 = 28,311,552 B
    __hip_bfloat16* wbuf = (__hip_bfloat16*)(ws + 113295360);    // up to 2,359,296 bf16 = 4,718,592 B
    // total ws use: 118,013,952 B

    // patch embedding
    patchify_kernel<<<27648, 256, 0, stream>>>(x, (unsigned short*)patches);
    convT_kernel<<<dim3(768 / 32, 1536 / 32), 256, 0, stream>>>(patch_w, wbuf, 1536, 768);
    gemm_bt_kernel<true, false, false, false><<<dim3(6, 36), 256, 0, stream>>>(
        patches, wbuf, patch_b, nullptr, tok, nullptr, 4608, 768, 1536);

    for (int l = 0; l < 4; l++) {
        // attn sub-block
        ln_kernel<__hip_bfloat16><<<4608, 256, 0, stream>>>(tok, ln1_g + l * 768, ln1_b + l * 768, h_bf);
        convT_kernel<<<dim3(2304 / 32, 768 / 32), 256, 0, stream>>>(w_qkv + (size_t)l * 768 * 2304, wbuf, 768, 2304);
        gemm_bt_kernel<false, false, false, false><<<dim3(18, 36), 256, 0, stream>>>(
            h_bf, wbuf, nullptr, nullptr, qkv, nullptr, 4608, 2304, 768);
        attn_kernel<<<dim3(36, 12, 8), 256, 0, stream>>>(
            qkv, bias_att + (size_t)l * 12 * 576 * 576, (unsigned short*)o_bf);
        convT_kernel<<<dim3(768 / 32, 768 / 32), 256, 0, stream>>>(w_out + (size_t)l * 768 * 768, wbuf, 768, 768);
        gemm_bt_kernel<false, true, false, false><<<dim3(6, 36), 256, 0, stream>>>(
            o_bf, wbuf, nullptr, tok, tok, nullptr, 4608, 768, 768);
        // mlp sub-block
        ln_kernel<__hip_bfloat16><<<4608, 256, 0, stream>>>(tok, ln2_g + l * 768, ln2_b + l * 768, h_bf);
        convT_kernel<<<dim3(3072 / 32, 768 / 32), 256, 0, stream>>>(w1 + (size_t)l * 768 * 3072, wbuf, 768, 3072);
        gemm_bt_kernel<true, false, true, true><<<dim3(24, 36), 256, 0, stream>>>(
            h_bf, wbuf, b1 + l * 3072, nullptr, nullptr, hid_bf, 4608, 3072, 768);
        convT_kernel<<<dim3(768 / 32, 3072 / 32), 256, 0, stream>>>(w2 + (size_t)l * 3072 * 768, wbuf, 3072, 768);
        gemm_bt_kernel<true, true, false, false><<<dim3(6, 36), 256, 0, stream>>>(
            hid_bf, wbuf, b2 + l * 768, tok, tok, nullptr, 4608, 768, 3072);
    }

    pool_kernel<<<dim3(3, 8), 256, 0, stream>>>(tok, pooled);
    ln_kernel<float><<<8, 256, 0, stream>>>(pooled, lnh_g, lnh_b, pooledln);
    head_kernel<<<dim3(4, 8), 256, 0, stream>>>(pooledln, w_head, b_head, out);
}

// Round 2
// 1207.215 us; speedup vs baseline: 1.8444x; 1.8444x over previous
//
#include <hip/hip_runtime.h>
#include <hip/hip_bf16.h>

typedef __attribute__((ext_vector_type(8))) short bf16x8;
typedef __attribute__((ext_vector_type(4))) float f32x4;

#define DEVI __device__ __forceinline__

DEVI unsigned short f2bf_bits(float f) {
    __hip_bfloat16 h = __float2bfloat16(f);
    return *reinterpret_cast<unsigned short*>(&h);
}

// async global->LDS, 16B per lane. LDS dest is wave-uniform base + lane*16; we pass the
// per-lane address whose lane-0 value is the base and whose per-lane layout matches.
DEVI void gload_lds16(const void* g, void* lds) {
    __builtin_amdgcn_global_load_lds(
        (const __attribute__((address_space(1))) unsigned int*)g,
        (__attribute__((address_space(3))) unsigned int*)lds, 16, 0, 0);
}

// ---------------- patchify: x[B,C,384,384] -> patches bf16 [4608][1536] ----------------
__global__ __launch_bounds__(256) void patchify_kernel(const float* __restrict__ x,
                                                       unsigned short* __restrict__ patches)
{
    size_t i = (size_t)blockIdx.x * 256 + threadIdx.x;   // 8*6*384*384 = 7,077,888 exactly
    int j = (int)(i % 384);
    size_t t = i / 384;
    int r = (int)(t % 384); t /= 384;
    int c = (int)(t % 6);
    int b = (int)(t / 6);
    int gh = r >> 4, p1 = r & 15, gw = j >> 4, p2 = j & 15;
    int prow = b * 576 + gh * 24 + gw;
    int pcol = (p1 * 16 + p2) * 6 + c;
    patches[(size_t)prow * 1536 + pcol] = f2bf_bits(x[i]);
}

// ---------------- weight convert + transpose: W f32 [K][N] -> Wt bf16 [N][K] ----------------
__global__ __launch_bounds__(256) void convT_kernel(const float* __restrict__ W,
                                                    __hip_bfloat16* __restrict__ Wt,
                                                    int K, int N)
{
    __shared__ float tile[32][33];
    int n0 = blockIdx.x * 32, k0 = blockIdx.y * 32;
    int tx = threadIdx.x & 31, ty = threadIdx.x >> 5;   // ty 0..7
#pragma unroll
    for (int i = 0; i < 4; i++)
        tile[ty + 8 * i][tx] = W[(size_t)(k0 + ty + 8 * i) * N + n0 + tx];
    __syncthreads();
#pragma unroll
    for (int i = 0; i < 4; i++)
        Wt[(size_t)(n0 + ty + 8 * i) * K + k0 + tx] = __float2bfloat16(tile[tx][ty + 8 * i]);
}

// ---------------- layernorm over 768 cols ----------------
DEVI void st_ln(float* p, float v) { *p = v; }
DEVI void st_ln(__hip_bfloat16* p, float v) { *p = __float2bfloat16(v); }

template <typename OutT>
__global__ __launch_bounds__(256) void ln_kernel(const float* __restrict__ x,
                                                 const float* __restrict__ g,
                                                 const float* __restrict__ b,
                                                 OutT* __restrict__ out)
{
    int row = blockIdx.x, tid = threadIdx.x;
    const float* xr = x + (size_t)row * 768;
    float v0 = xr[tid], v1 = xr[tid + 256], v2 = xr[tid + 512];
    float s = v0 + v1 + v2;
    float s2 = v0 * v0 + v1 * v1 + v2 * v2;
#pragma unroll
    for (int m = 32; m >= 1; m >>= 1) { s += __shfl_xor(s, m); s2 += __shfl_xor(s2, m); }
    __shared__ float red[8];
    int w = tid >> 6;
    if ((tid & 63) == 0) { red[w] = s; red[4 + w] = s2; }
    __syncthreads();
    s = red[0] + red[1] + red[2] + red[3];
    s2 = red[4] + red[5] + red[6] + red[7];
    float mean = s * (1.0f / 768.0f);
    float var = s2 * (1.0f / 768.0f) - mean * mean;
    float rstd = rsqrtf(var + 1e-5f);
    OutT* orow = out + (size_t)row * 768;
    st_ln(&orow[tid], (v0 - mean) * rstd * g[tid] + b[tid]);
    st_ln(&orow[tid + 256], (v1 - mean) * rstd * g[tid + 256] + b[tid + 256]);
    st_ln(&orow[tid + 512], (v2 - mean) * rstd * g[tid + 512] + b[tid + 512]);
}

// ---------------- bf16 MFMA GEMM (m97 structure): C[M,N] = A[M,K] @ Bt[N,K]^T ----------------
// 128x128 tile, BK=32, 4 waves (2x2 of 64x64), linear LDS + global_load_lds width 16.
template <bool BIAS, bool RESID, bool GELU, bool BF16OUT>
__global__ __launch_bounds__(256) void gemm_bt_kernel(
    const __hip_bfloat16* __restrict__ A,
    const __hip_bfloat16* __restrict__ Bt,
    const float* __restrict__ bias,
    const float* __restrict__ resid,
    float* __restrict__ Cf,
    __hip_bfloat16* __restrict__ Cb,
    int M, int N, int K)
{
    __shared__ __align__(16) __hip_bfloat16 As[128 * 32];   // [row][k] 64B rows, linear
    __shared__ __align__(16) __hip_bfloat16 Bs[128 * 32];
    const int tid = threadIdx.x;
    const int wid = tid >> 6, lane = tid & 63;
    const int g = lane >> 4, l16 = lane & 15;
    const int wm = (wid >> 1) * 64, wn = (wid & 1) * 64;
    const int bm = blockIdx.y * 128, bn = blockIdx.x * 128;
    const int sr0 = lane >> 2, sc0 = (lane & 3) * 8;        // staging: 16 rows x 64B per wave-load

    f32x4 acc[4][4] = {};

    for (int k0 = 0; k0 < K; k0 += 32) {
#pragma unroll
        for (int t = 0; t < 2; t++) {
            int r = (wid * 2 + t) * 16 + sr0;
            gload_lds16(&A[(size_t)(bm + r) * K + k0 + sc0], &As[r * 32 + sc0]);
            gload_lds16(&Bt[(size_t)(bn + r) * K + k0 + sc0], &Bs[r * 32 + sc0]);
        }
        __syncthreads();

        bf16x8 af[4], bfr[4];
#pragma unroll
        for (int mi = 0; mi < 4; mi++)
            af[mi] = *(const bf16x8*)&As[(wm + mi * 16 + l16) * 32 + g * 8];
#pragma unroll
        for (int ni = 0; ni < 4; ni++)
            bfr[ni] = *(const bf16x8*)&Bs[(wn + ni * 16 + l16) * 32 + g * 8];
#pragma unroll
        for (int mi = 0; mi < 4; mi++)
#pragma unroll
            for (int ni = 0; ni < 4; ni++)
                acc[mi][ni] = __builtin_amdgcn_mfma_f32_16x16x32_bf16(af[mi], bfr[ni], acc[mi][ni], 0, 0, 0);
        __syncthreads();
    }

#pragma unroll
    for (int mi = 0; mi < 4; mi++) {
#pragma unroll
        for (int ni = 0; ni < 4; ni++) {
            int gcol = bn + wn + ni * 16 + l16;
            float bval = 0.0f;
            if (BIAS) bval = bias[gcol];
#pragma unroll
            for (int r = 0; r < 4; r++) {
                int grow = bm + wm + mi * 16 + 4 * g + r;   // C/D: row=(lane>>4)*4+reg, col=lane&15
                float v = acc[mi][ni][r] + bval;
                if (GELU) v = 0.5f * v * (1.0f + erff(v * 0.70710678118654752f));
                if (RESID) v += resid[(size_t)grow * N + gcol];
                if (BF16OUT) Cb[(size_t)grow * N + gcol] = __float2bfloat16(v);
                else Cf[(size_t)grow * N + gcol] = v;
            }
        }
    }
}

// ---------------- MFMA flash attention: softmax(q@k^T*scale + bias) @ v ----------------
// grid (9 qtiles, 12 heads, 8 batch), block 256 = 4 waves x 16 queries. Online softmax.
// All LDS tiles use 72-elem (144B) row stride: 16B-aligned for b128 and bank-spread.
DEVI void stage16f(const float* __restrict__ src, __hip_bfloat16* dst)
{
#pragma unroll
    for (int i = 0; i < 4; i++) {
        float4 v = ((const float4*)src)[i];
        ushort4 u = { f2bf_bits(v.x), f2bf_bits(v.y), f2bf_bits(v.z), f2bf_bits(v.w) };
        ((ushort4*)dst)[i] = u;
    }
}

__global__ __launch_bounds__(256) void attn_kernel(const float* __restrict__ qkv,
                                                   const float* __restrict__ bias,   // [12][576][576] this layer
                                                   unsigned short* __restrict__ o)   // bf16 [4608][768]
{
    const int qt = blockIdx.x, h = blockIdx.y, bb = blockIdx.z;
    const int q0 = qt * 64;
    const int tid = threadIdx.x;
    const int wq = tid >> 6, lane = tid & 63, g = lane >> 4, l16 = lane & 15;

    __shared__ __align__(16) __hip_bfloat16 Qs[64 * 72];
    __shared__ __align__(16) __hip_bfloat16 Ks[64 * 72];
    __shared__ __align__(16) __hip_bfloat16 Vt[64 * 72];    // V^T: [d][key]
    __shared__ __align__(16) __hip_bfloat16 Ps[4][16 * 72]; // per-wave P tile [qrow][key]

    // stage Q tile (64 q x 64 d), bf16
    {
        int r = tid >> 2, cb = (tid & 3) * 16;
        stage16f(&qkv[(size_t)(bb * 576 + q0 + r) * 2304 + h * 64 + cb], &Qs[r * 72 + cb]);
    }
    __syncthreads();
    bf16x8 qf0 = *(const bf16x8*)&Qs[(wq * 16 + l16) * 72 + g * 8];
    bf16x8 qf1 = *(const bf16x8*)&Qs[(wq * 16 + l16) * 72 + 32 + g * 8];

    float m_r[4] = {-1e30f, -1e30f, -1e30f, -1e30f};
    float l_r[4] = {0.f, 0.f, 0.f, 0.f};
    f32x4 oa[4] = {};
    const float* bias_h = bias + (size_t)h * 576 * 576;
    const float scale = 0.125f;

    for (int kt = 0; kt < 576; kt += 64) {
        // stage K [key][d] and V^T [d][key]
        {
            int r = tid >> 2, cb = (tid & 3) * 16;
            stage16f(&qkv[(size_t)(bb * 576 + kt + r) * 2304 + 768 + h * 64 + cb], &Ks[r * 72 + cb]);
            int key = tid & 63, d0 = (tid >> 6) * 16;
            const float* vs = &qkv[(size_t)(bb * 576 + kt + key) * 2304 + 1536 + h * 64 + d0];
#pragma unroll
            for (int i = 0; i < 4; i++) {
                float4 v = ((const float4*)vs)[i];
                Vt[(d0 + 4 * i + 0) * 72 + key] = __float2bfloat16(v.x);
                Vt[(d0 + 4 * i + 1) * 72 + key] = __float2bfloat16(v.y);
                Vt[(d0 + 4 * i + 2) * 72 + key] = __float2bfloat16(v.z);
                Vt[(d0 + 4 * i + 3) * 72 + key] = __float2bfloat16(v.w);
            }
        }
        __syncthreads();

        // bias prefetch (independent of QK mfma; compiler overlaps)
        float bl[4][4];
#pragma unroll
        for (int kc = 0; kc < 4; kc++)
#pragma unroll
            for (int r = 0; r < 4; r++) {
                int q = q0 + wq * 16 + 4 * g + r;
                bl[kc][r] = bias_h[(size_t)q * 576 + kt + kc * 16 + l16];
            }

        // QK^T: 4 key-col tiles x 2 d-halves
        f32x4 sc[4] = {};
#pragma unroll
        for (int kc = 0; kc < 4; kc++) {
            bf16x8 kf0 = *(const bf16x8*)&Ks[(kc * 16 + l16) * 72 + g * 8];
            bf16x8 kf1 = *(const bf16x8*)&Ks[(kc * 16 + l16) * 72 + 32 + g * 8];
            sc[kc] = __builtin_amdgcn_mfma_f32_16x16x32_bf16(qf0, kf0, sc[kc], 0, 0, 0);
            sc[kc] = __builtin_amdgcn_mfma_f32_16x16x32_bf16(qf1, kf1, sc[kc], 0, 0, 0);
        }

        // scores + tile max
        float sv[4][4], mt[4] = {-1e30f, -1e30f, -1e30f, -1e30f};
#pragma unroll
        for (int kc = 0; kc < 4; kc++)
#pragma unroll
            for (int r = 0; r < 4; r++) {
                float s = sc[kc][r] * scale + bl[kc][r];
                sv[kc][r] = s;
                mt[r] = fmaxf(mt[r], s);
            }
#pragma unroll
        for (int r = 0; r < 4; r++)
#pragma unroll
            for (int m = 1; m < 16; m <<= 1) mt[r] = fmaxf(mt[r], __shfl_xor(mt[r], m));

        // online-softmax update
        float sf[4];
#pragma unroll
        for (int r = 0; r < 4; r++) {
            float mn = fmaxf(m_r[r], mt[r]);
            sf[r] = __expf(m_r[r] - mn);
            m_r[r] = mn;
        }
        float rs[4] = {0.f, 0.f, 0.f, 0.f};
#pragma unroll
        for (int kc = 0; kc < 4; kc++)
#pragma unroll
            for (int r = 0; r < 4; r++) {
                float p = __expf(sv[kc][r] - m_r[r]);
                rs[r] += p;
                Ps[wq][(4 * g + r) * 72 + kc * 16 + l16] = __float2bfloat16(p);
            }
#pragma unroll
        for (int r = 0; r < 4; r++) {
#pragma unroll
            for (int m = 1; m < 16; m <<= 1) rs[r] += __shfl_xor(rs[r], m);
            l_r[r] = l_r[r] * sf[r] + rs[r];
        }
#pragma unroll
        for (int dt = 0; dt < 4; dt++)
#pragma unroll
            for (int r = 0; r < 4; r++) oa[dt][r] *= sf[r];

        // in-wave LDS fence: P writes (cross-lane) must land before A-fragment reads
        asm volatile("s_waitcnt lgkmcnt(0)" ::: "memory");

        // PV: 2 key-halves (K=32) x 4 d-tiles
#pragma unroll
        for (int s = 0; s < 2; s++) {
            bf16x8 pf = *(const bf16x8*)&Ps[wq][l16 * 72 + s * 32 + g * 8];
#pragma unroll
            for (int dt = 0; dt < 4; dt++) {
                bf16x8 vf = *(const bf16x8*)&Vt[(dt * 16 + l16) * 72 + s * 32 + g * 8];
                oa[dt] = __builtin_amdgcn_mfma_f32_16x16x32_bf16(pf, vf, oa[dt], 0, 0, 0);
            }
        }
        __syncthreads();
    }

    // epilogue: normalize + write bf16
#pragma unroll
    for (int dt = 0; dt < 4; dt++)
#pragma unroll
        for (int r = 0; r < 4; r++) {
            int q = q0 + wq * 16 + 4 * g + r;
            float v = oa[dt][r] / l_r[r];
            o[(size_t)(bb * 576 + q) * 768 + h * 64 + dt * 16 + l16] = f2bf_bits(v);
        }
}

// ---------------- mean pool over 576 tokens ----------------
__global__ __launch_bounds__(256) void pool_kernel(const float* __restrict__ tok, float* __restrict__ pooled)
{
    int d = blockIdx.x * 256 + threadIdx.x;   // grid.x = 3
    int b = blockIdx.y;
    float s = 0.0f;
    for (int n = 0; n < 576; n++) s += tok[(size_t)(b * 576 + n) * 768 + d];
    pooled[b * 768 + d] = s * (1.0f / 576.0f);
}

// ---------------- classifier head ----------------
__global__ __launch_bounds__(256) void head_kernel(const float* __restrict__ lnp,
                                                   const float* __restrict__ w,
                                                   const float* __restrict__ bh,
                                                   float* __restrict__ out)
{
    int c = blockIdx.x * 256 + threadIdx.x;
    int b = blockIdx.y;
    if (c >= 1000) return;
    float s = bh[c];
    for (int d = 0; d < 768; d++) s += lnp[b * 768 + d] * w[(size_t)d * 1000 + c];
    out[b * 1000 + c] = s;
}

extern "C" void kernel_launch(void* const* d_in, const int* in_sizes, int n_in,
                              void* d_out, int out_size, void* d_ws, size_t ws_size,
                              hipStream_t stream)
{
    const float* x = (const float*)d_in[0];
    const float* patch_w = (const float*)d_in[1];
    const float* patch_b = (const float*)d_in[2];
    const float* ln1_g = (const float*)d_in[3];
    const float* ln1_b = (const float*)d_in[4];
    const float* w_qkv = (const float*)d_in[5];
    const float* bias_att = (const float*)d_in[6];
    const float* w_out = (const float*)d_in[7];
    const float* ln2_g = (const float*)d_in[8];
    const float* ln2_b = (const float*)d_in[9];
    const float* w1 = (const float*)d_in[10];
    const float* b1 = (const float*)d_in[11];
    const float* w2 = (const float*)d_in[12];
    const float* b2 = (const float*)d_in[13];
    const float* lnh_g = (const float*)d_in[14];
    const float* lnh_b = (const float*)d_in[15];
    const float* w_head = (const float*)d_in[16];
    const float* b_head = (const float*)d_in[17];
    float* out = (float*)d_out;

    char* ws = (char*)d_ws;
    float* tok = (float*)(ws + 0);                               // 4608*768 f32   = 14,155,776 B
    float* qkv = (float*)(ws + 14155776);                        // 4608*2304 f32  = 42,467,328 B
    float* pooled = (float*)(ws + 56623104);                     // 8*768 f32
    float* pooledln = (float*)(ws + 56647680);                   // 8*768 f32
    __hip_bfloat16* patches = (__hip_bfloat16*)(ws + 56672256);  // 4608*1536 bf16 = 14,155,776 B
    __hip_bfloat16* h_bf = (__hip_bfloat16*)(ws + 70828032);     // 4608*768 bf16  =  7,077,888 B
    __hip_bfloat16* o_bf = (__hip_bfloat16*)(ws + 77905920);     // 4608*768 bf16  =  7,077,888 B
    __hip_bfloat16* hid_bf = (__hip_bfloat16*)(ws + 84983808);   // 4608*3072 bf16 = 28,311,552 B
    __hip_bfloat16* wbuf = (__hip_bfloat16*)(ws + 113295360);    // up to 2,359,296 bf16 = 4,718,592 B

    // patch embedding
    patchify_kernel<<<27648, 256, 0, stream>>>(x, (unsigned short*)patches);
    convT_kernel<<<dim3(768 / 32, 1536 / 32), 256, 0, stream>>>(patch_w, wbuf, 1536, 768);
    gemm_bt_kernel<true, false, false, false><<<dim3(6, 36), 256, 0, stream>>>(
        patches, wbuf, patch_b, nullptr, tok, nullptr, 4608, 768, 1536);

    for (int l = 0; l < 4; l++) {
        // attn sub-block
        ln_kernel<__hip_bfloat16><<<4608, 256, 0, stream>>>(tok, ln1_g + l * 768, ln1_b + l * 768, h_bf);
        convT_kernel<<<dim3(2304 / 32, 768 / 32), 256, 0, stream>>>(w_qkv + (size_t)l * 768 * 2304, wbuf, 768, 2304);
        gemm_bt_kernel<false, false, false, false><<<dim3(18, 36), 256, 0, stream>>>(
            h_bf, wbuf, nullptr, nullptr, qkv, nullptr, 4608, 2304, 768);
        attn_kernel<<<dim3(9, 12, 8), 256, 0, stream>>>(
            qkv, bias_att + (size_t)l * 12 * 576 * 576, (unsigned short*)o_bf);
        convT_kernel<<<dim3(768 / 32, 768 / 32), 256, 0, stream>>>(w_out + (size_t)l * 768 * 768, wbuf, 768, 768);
        gemm_bt_kernel<false, true, false, false><<<dim3(6, 36), 256, 0, stream>>>(
            o_bf, wbuf, nullptr, tok, tok, nullptr, 4608, 768, 768);
        // mlp sub-block
        ln_kernel<__hip_bfloat16><<<4608, 256, 0, stream>>>(tok, ln2_g + l * 768, ln2_b + l * 768, h_bf);
        convT_kernel<<<dim3(3072 / 32, 768 / 32), 256, 0, stream>>>(w1 + (size_t)l * 768 * 3072, wbuf, 768, 3072);
        gemm_bt_kernel<true, false, true, true><<<dim3(24, 36), 256, 0, stream>>>(
            h_bf, wbuf, b1 + l * 3072, nullptr, nullptr, hid_bf, 4608, 3072, 768);
        convT_kernel<<<dim3(768 / 32, 3072 / 32), 256, 0, stream>>>(w2 + (size_t)l * 3072 * 768, wbuf, 3072, 768);
        gemm_bt_kernel<true, true, false, false><<<dim3(6, 36), 256, 0, stream>>>(
            hid_bf, wbuf, b2 + l * 768, tok, tok, nullptr, 4608, 768, 3072);
    }

    pool_kernel<<<dim3(3, 8), 256, 0, stream>>>(tok, pooled);
    ln_kernel<float><<<8, 256, 0, stream>>>(pooled, lnh_g, lnh_b, pooledln);
    head_kernel<<<dim3(4, 8), 256, 0, stream>>>(pooledln, w_head, b_head, out);
}

// Round 3
// 1082.678 us; speedup vs baseline: 2.0565x; 1.1150x over previous
//
#include <hip/hip_runtime.h>
#include <hip/hip_bf16.h>

typedef __attribute__((ext_vector_type(8))) short bf16x8;
typedef __attribute__((ext_vector_type(4))) float f32x4;

#define DEVI __device__ __forceinline__

DEVI unsigned short f2bf_bits(float f) {
    __hip_bfloat16 h = __float2bfloat16(f);
    return *reinterpret_cast<unsigned short*>(&h);
}

// async global->LDS, 16B per lane. LDS dest is wave-uniform base + lane*16.
DEVI void gload_lds16(const void* g, void* lds) {
    __builtin_amdgcn_global_load_lds(
        (const __attribute__((address_space(1))) unsigned int*)g,
        (__attribute__((address_space(3))) unsigned int*)lds, 16, 0, 0);
}

// ---------------- patchify: x[B,C,384,384] -> patches bf16 [4608][1536] ----------------
__global__ __launch_bounds__(256) void patchify_kernel(const float* __restrict__ x,
                                                       unsigned short* __restrict__ patches)
{
    size_t i = (size_t)blockIdx.x * 256 + threadIdx.x;   // 8*6*384*384 = 7,077,888 exactly
    int j = (int)(i % 384);
    size_t t = i / 384;
    int r = (int)(t % 384); t /= 384;
    int c = (int)(t % 6);
    int b = (int)(t / 6);
    int gh = r >> 4, p1 = r & 15, gw = j >> 4, p2 = j & 15;
    int prow = b * 576 + gh * 24 + gw;
    int pcol = (p1 * 16 + p2) * 6 + c;
    patches[(size_t)prow * 1536 + pcol] = f2bf_bits(x[i]);
}

// ---------------- weight convert + transpose: W f32 [K][N] -> Wt bf16 [N][K] ----------------
__global__ __launch_bounds__(256) void convT_kernel(const float* __restrict__ W,
                                                    __hip_bfloat16* __restrict__ Wt,
                                                    int K, int N)
{
    __shared__ float tile[32][33];
    int n0 = blockIdx.x * 32, k0 = blockIdx.y * 32;
    int tx = threadIdx.x & 31, ty = threadIdx.x >> 5;   // ty 0..7
#pragma unroll
    for (int i = 0; i < 4; i++)
        tile[ty + 8 * i][tx] = W[(size_t)(k0 + ty + 8 * i) * N + n0 + tx];
    __syncthreads();
#pragma unroll
    for (int i = 0; i < 4; i++)
        Wt[(size_t)(n0 + ty + 8 * i) * K + k0 + tx] = __float2bfloat16(tile[tx][ty + 8 * i]);
}

// ---------------- layernorm over 768 cols ----------------
DEVI void st_ln(float* p, float v) { *p = v; }
DEVI void st_ln(__hip_bfloat16* p, float v) { *p = __float2bfloat16(v); }

template <typename OutT>
__global__ __launch_bounds__(256) void ln_kernel(const float* __restrict__ x,
                                                 const float* __restrict__ g,
                                                 const float* __restrict__ b,
                                                 OutT* __restrict__ out)
{
    int row = blockIdx.x, tid = threadIdx.x;
    const float* xr = x + (size_t)row * 768;
    float v0 = xr[tid], v1 = xr[tid + 256], v2 = xr[tid + 512];
    float s = v0 + v1 + v2;
    float s2 = v0 * v0 + v1 * v1 + v2 * v2;
#pragma unroll
    for (int m = 32; m >= 1; m >>= 1) { s += __shfl_xor(s, m); s2 += __shfl_xor(s2, m); }
    __shared__ float red[8];
    int w = tid >> 6;
    if ((tid & 63) == 0) { red[w] = s; red[4 + w] = s2; }
    __syncthreads();
    s = red[0] + red[1] + red[2] + red[3];
    s2 = red[4] + red[5] + red[6] + red[7];
    float mean = s * (1.0f / 768.0f);
    float var = s2 * (1.0f / 768.0f) - mean * mean;
    float rstd = rsqrtf(var + 1e-5f);
    OutT* orow = out + (size_t)row * 768;
    st_ln(&orow[tid], (v0 - mean) * rstd * g[tid] + b[tid]);
    st_ln(&orow[tid + 256], (v1 - mean) * rstd * g[tid + 256] + b[tid + 256]);
    st_ln(&orow[tid + 512], (v2 - mean) * rstd * g[tid + 512] + b[tid + 512]);
}

// ---------------- bf16 MFMA GEMM, 2-phase double-buffered pipeline ----------------
// C[M,N] = A[M,K] @ Bt[N,K]^T. Tile BM x 128, BK=32, 4 waves (2x2), linear LDS,
// global_load_lds width 16. Stage next K-tile BEFORE computing current one; the single
// __syncthreads per step drains vmcnt AFTER the MFMAs, hiding HBM latency under compute.
template <int BM, bool BIAS, bool RESID, bool GELU, bool BF16OUT>
__global__ __launch_bounds__(256) void gemm_bt_kernel(
    const __hip_bfloat16* __restrict__ A,
    const __hip_bfloat16* __restrict__ Bt,
    const float* __restrict__ bias,
    const float* __restrict__ resid,
    float* __restrict__ Cf,
    __hip_bfloat16* __restrict__ Cb,
    int M, int N, int K)
{
    constexpr int MREP = BM / 32;
    __shared__ __align__(16) __hip_bfloat16 As[2][BM * 32];
    __shared__ __align__(16) __hip_bfloat16 Bs[2][128 * 32];
    const int tid = threadIdx.x;
    const int wid = tid >> 6, lane = tid & 63;
    const int g = lane >> 4, l16 = lane & 15;
    const int wm = (wid >> 1) * (BM / 2), wn = (wid & 1) * 64;
    const int bm = blockIdx.y * BM, bn = blockIdx.x * 128;
    const int sr = tid >> 2, sc = (tid & 3) * 8;   // 256 thr = 64 rows x 64B per round

    f32x4 acc[MREP][4] = {};
    const int nt = K >> 5;

    auto stage = [&](int buf, int t) {
        const int k0 = t * 32;
#pragma unroll
        for (int i = 0; i < BM / 64; i++)
            gload_lds16(&A[(size_t)(bm + i * 64 + sr) * K + k0 + sc], &As[buf][(i * 64 + sr) * 32 + sc]);
#pragma unroll
        for (int i = 0; i < 2; i++)
            gload_lds16(&Bt[(size_t)(bn + i * 64 + sr) * K + k0 + sc], &Bs[buf][(i * 64 + sr) * 32 + sc]);
    };

    stage(0, 0);
    __syncthreads();

    int cur = 0;
    for (int t = 0; t < nt; t++) {
        if (t + 1 < nt) stage(cur ^ 1, t + 1);
        bf16x8 af[MREP], bfr[4];
#pragma unroll
        for (int mi = 0; mi < MREP; mi++)
            af[mi] = *(const bf16x8*)&As[cur][(wm + mi * 16 + l16) * 32 + g * 8];
#pragma unroll
        for (int ni = 0; ni < 4; ni++)
            bfr[ni] = *(const bf16x8*)&Bs[cur][(wn + ni * 16 + l16) * 32 + g * 8];
#pragma unroll
        for (int mi = 0; mi < MREP; mi++)
#pragma unroll
            for (int ni = 0; ni < 4; ni++)
                acc[mi][ni] = __builtin_amdgcn_mfma_f32_16x16x32_bf16(af[mi], bfr[ni], acc[mi][ni], 0, 0, 0);
        __syncthreads();
        cur ^= 1;
    }

#pragma unroll
    for (int mi = 0; mi < MREP; mi++) {
#pragma unroll
        for (int ni = 0; ni < 4; ni++) {
            int gcol = bn + wn + ni * 16 + l16;
            float bval = 0.0f;
            if (BIAS) bval = bias[gcol];
#pragma unroll
            for (int r = 0; r < 4; r++) {
                int grow = bm + wm + mi * 16 + 4 * g + r;   // C/D: row=(lane>>4)*4+reg, col=lane&15
                float v = acc[mi][ni][r] + bval;
                if (GELU) v = 0.5f * v * (1.0f + erff(v * 0.70710678118654752f));
                if (RESID) v += resid[(size_t)grow * N + gcol];
                if (BF16OUT) Cb[(size_t)grow * N + gcol] = __float2bfloat16(v);
                else Cf[(size_t)grow * N + gcol] = v;
            }
        }
    }
}

// ---------------- MFMA flash attention: softmax(q@k^T*scale + bias) @ v ----------------
DEVI void stage16f(const float* __restrict__ src, __hip_bfloat16* dst)
{
#pragma unroll
    for (int i = 0; i < 4; i++) {
        float4 v = ((const float4*)src)[i];
        ushort4 u = { f2bf_bits(v.x), f2bf_bits(v.y), f2bf_bits(v.z), f2bf_bits(v.w) };
        ((ushort4*)dst)[i] = u;
    }
}

__global__ __launch_bounds__(256) void attn_kernel(const float* __restrict__ qkv,
                                                   const float* __restrict__ bias,   // [12][576][576] this layer
                                                   unsigned short* __restrict__ o)   // bf16 [4608][768]
{
    const int qt = blockIdx.x, h = blockIdx.y, bb = blockIdx.z;
    const int q0 = qt * 64;
    const int tid = threadIdx.x;
    const int wq = tid >> 6, lane = tid & 63, g = lane >> 4, l16 = lane & 15;

    __shared__ __align__(16) __hip_bfloat16 Qs[64 * 72];
    __shared__ __align__(16) __hip_bfloat16 Ks[64 * 72];
    __shared__ __align__(16) __hip_bfloat16 Vt[64 * 72];    // V^T: [d][key]
    __shared__ __align__(16) __hip_bfloat16 Ps[4][16 * 72]; // per-wave P tile [qrow][key]

    {
        int r = tid >> 2, cb = (tid & 3) * 16;
        stage16f(&qkv[(size_t)(bb * 576 + q0 + r) * 2304 + h * 64 + cb], &Qs[r * 72 + cb]);
    }
    __syncthreads();
    bf16x8 qf0 = *(const bf16x8*)&Qs[(wq * 16 + l16) * 72 + g * 8];
    bf16x8 qf1 = *(const bf16x8*)&Qs[(wq * 16 + l16) * 72 + 32 + g * 8];

    float m_r[4] = {-1e30f, -1e30f, -1e30f, -1e30f};
    float l_r[4] = {0.f, 0.f, 0.f, 0.f};
    f32x4 oa[4] = {};
    const float* bias_h = bias + (size_t)h * 576 * 576;
    const float scale = 0.125f;

    for (int kt = 0; kt < 576; kt += 64) {
        {
            int r = tid >> 2, cb = (tid & 3) * 16;
            stage16f(&qkv[(size_t)(bb * 576 + kt + r) * 2304 + 768 + h * 64 + cb], &Ks[r * 72 + cb]);
            int key = tid & 63, d0 = (tid >> 6) * 16;
            const float* vs = &qkv[(size_t)(bb * 576 + kt + key) * 2304 + 1536 + h * 64 + d0];
#pragma unroll
            for (int i = 0; i < 4; i++) {
                float4 v = ((const float4*)vs)[i];
                Vt[(d0 + 4 * i + 0) * 72 + key] = __float2bfloat16(v.x);
                Vt[(d0 + 4 * i + 1) * 72 + key] = __float2bfloat16(v.y);
                Vt[(d0 + 4 * i + 2) * 72 + key] = __float2bfloat16(v.z);
                Vt[(d0 + 4 * i + 3) * 72 + key] = __float2bfloat16(v.w);
            }
        }
        __syncthreads();

        float bl[4][4];
#pragma unroll
        for (int kc = 0; kc < 4; kc++)
#pragma unroll
            for (int r = 0; r < 4; r++) {
                int q = q0 + wq * 16 + 4 * g + r;
                bl[kc][r] = bias_h[(size_t)q * 576 + kt + kc * 16 + l16];
            }

        f32x4 sc[4] = {};
#pragma unroll
        for (int kc = 0; kc < 4; kc++) {
            bf16x8 kf0 = *(const bf16x8*)&Ks[(kc * 16 + l16) * 72 + g * 8];
            bf16x8 kf1 = *(const bf16x8*)&Ks[(kc * 16 + l16) * 72 + 32 + g * 8];
            sc[kc] = __builtin_amdgcn_mfma_f32_16x16x32_bf16(qf0, kf0, sc[kc], 0, 0, 0);
            sc[kc] = __builtin_amdgcn_mfma_f32_16x16x32_bf16(qf1, kf1, sc[kc], 0, 0, 0);
        }

        float sv[4][4], mt[4] = {-1e30f, -1e30f, -1e30f, -1e30f};
#pragma unroll
        for (int kc = 0; kc < 4; kc++)
#pragma unroll
            for (int r = 0; r < 4; r++) {
                float s = sc[kc][r] * scale + bl[kc][r];
                sv[kc][r] = s;
                mt[r] = fmaxf(mt[r], s);
            }
#pragma unroll
        for (int r = 0; r < 4; r++)
#pragma unroll
            for (int m = 1; m < 16; m <<= 1) mt[r] = fmaxf(mt[r], __shfl_xor(mt[r], m));

        float sf[4];
#pragma unroll
        for (int r = 0; r < 4; r++) {
            float mn = fmaxf(m_r[r], mt[r]);
            sf[r] = __expf(m_r[r] - mn);
            m_r[r] = mn;
        }
        float rs[4] = {0.f, 0.f, 0.f, 0.f};
#pragma unroll
        for (int kc = 0; kc < 4; kc++)
#pragma unroll
            for (int r = 0; r < 4; r++) {
                float p = __expf(sv[kc][r] - m_r[r]);
                rs[r] += p;
                Ps[wq][(4 * g + r) * 72 + kc * 16 + l16] = __float2bfloat16(p);
            }
#pragma unroll
        for (int r = 0; r < 4; r++) {
#pragma unroll
            for (int m = 1; m < 16; m <<= 1) rs[r] += __shfl_xor(rs[r], m);
            l_r[r] = l_r[r] * sf[r] + rs[r];
        }
#pragma unroll
        for (int dt = 0; dt < 4; dt++)
#pragma unroll
            for (int r = 0; r < 4; r++) oa[dt][r] *= sf[r];

        asm volatile("s_waitcnt lgkmcnt(0)" ::: "memory");

#pragma unroll
        for (int s = 0; s < 2; s++) {
            bf16x8 pf = *(const bf16x8*)&Ps[wq][l16 * 72 + s * 32 + g * 8];
#pragma unroll
            for (int dt = 0; dt < 4; dt++) {
                bf16x8 vf = *(const bf16x8*)&Vt[(dt * 16 + l16) * 72 + s * 32 + g * 8];
                oa[dt] = __builtin_amdgcn_mfma_f32_16x16x32_bf16(pf, vf, oa[dt], 0, 0, 0);
            }
        }
        __syncthreads();
    }

#pragma unroll
    for (int dt = 0; dt < 4; dt++)
#pragma unroll
        for (int r = 0; r < 4; r++) {
            int q = q0 + wq * 16 + 4 * g + r;
            float v = oa[dt][r] / l_r[r];
            o[(size_t)(bb * 576 + q) * 768 + h * 64 + dt * 16 + l16] = f2bf_bits(v);
        }
}

// ---------------- mean pool over 576 tokens ----------------
__global__ __launch_bounds__(256) void pool_kernel(const float* __restrict__ tok, float* __restrict__ pooled)
{
    int d = blockIdx.x * 256 + threadIdx.x;   // grid.x = 3
    int b = blockIdx.y;
    float s = 0.0f;
    for (int n = 0; n < 576; n++) s += tok[(size_t)(b * 576 + n) * 768 + d];
    pooled[b * 768 + d] = s * (1.0f / 576.0f);
}

// ---------------- classifier head ----------------
__global__ __launch_bounds__(256) void head_kernel(const float* __restrict__ lnp,
                                                   const float* __restrict__ w,
                                                   const float* __restrict__ bh,
                                                   float* __restrict__ out)
{
    int c = blockIdx.x * 256 + threadIdx.x;
    int b = blockIdx.y;
    if (c >= 1000) return;
    float s = bh[c];
    for (int d = 0; d < 768; d++) s += lnp[b * 768 + d] * w[(size_t)d * 1000 + c];
    out[b * 1000 + c] = s;
}

extern "C" void kernel_launch(void* const* d_in, const int* in_sizes, int n_in,
                              void* d_out, int out_size, void* d_ws, size_t ws_size,
                              hipStream_t stream)
{
    const float* x = (const float*)d_in[0];
    const float* patch_w = (const float*)d_in[1];
    const float* patch_b = (const float*)d_in[2];
    const float* ln1_g = (const float*)d_in[3];
    const float* ln1_b = (const float*)d_in[4];
    const float* w_qkv = (const float*)d_in[5];
    const float* bias_att = (const float*)d_in[6];
    const float* w_out = (const float*)d_in[7];
    const float* ln2_g = (const float*)d_in[8];
    const float* ln2_b = (const float*)d_in[9];
    const float* w1 = (const float*)d_in[10];
    const float* b1 = (const float*)d_in[11];
    const float* w2 = (const float*)d_in[12];
    const float* b2 = (const float*)d_in[13];
    const float* lnh_g = (const float*)d_in[14];
    const float* lnh_b = (const float*)d_in[15];
    const float* w_head = (const float*)d_in[16];
    const float* b_head = (const float*)d_in[17];
    float* out = (float*)d_out;

    char* ws = (char*)d_ws;
    float* tok = (float*)(ws + 0);                               // 4608*768 f32   = 14,155,776 B
    float* qkv = (float*)(ws + 14155776);                        // 4608*2304 f32  = 42,467,328 B
    float* pooled = (float*)(ws + 56623104);                     // 8*768 f32
    float* pooledln = (float*)(ws + 56647680);                   // 8*768 f32
    __hip_bfloat16* patches = (__hip_bfloat16*)(ws + 56672256);  // 4608*1536 bf16 = 14,155,776 B
    __hip_bfloat16* h_bf = (__hip_bfloat16*)(ws + 70828032);     // 4608*768 bf16  =  7,077,888 B
    __hip_bfloat16* o_bf = (__hip_bfloat16*)(ws + 77905920);     // 4608*768 bf16  =  7,077,888 B
    __hip_bfloat16* hid_bf = (__hip_bfloat16*)(ws + 84983808);   // 4608*3072 bf16 = 28,311,552 B
    __hip_bfloat16* wbuf = (__hip_bfloat16*)(ws + 113295360);    // up to 2,359,296 bf16 = 4,718,592 B

    // patch embedding
    patchify_kernel<<<27648, 256, 0, stream>>>(x, (unsigned short*)patches);
    convT_kernel<<<dim3(768 / 32, 1536 / 32), 256, 0, stream>>>(patch_w, wbuf, 1536, 768);
    gemm_bt_kernel<64, true, false, false, false><<<dim3(6, 72), 256, 0, stream>>>(
        patches, wbuf, patch_b, nullptr, tok, nullptr, 4608, 768, 1536);

    for (int l = 0; l < 4; l++) {
        // attn sub-block
        ln_kernel<__hip_bfloat16><<<4608, 256, 0, stream>>>(tok, ln1_g + l * 768, ln1_b + l * 768, h_bf);
        convT_kernel<<<dim3(2304 / 32, 768 / 32), 256, 0, stream>>>(w_qkv + (size_t)l * 768 * 2304, wbuf, 768, 2304);
        gemm_bt_kernel<128, false, false, false, false><<<dim3(18, 36), 256, 0, stream>>>(
            h_bf, wbuf, nullptr, nullptr, qkv, nullptr, 4608, 2304, 768);
        attn_kernel<<<dim3(9, 12, 8), 256, 0, stream>>>(
            qkv, bias_att + (size_t)l * 12 * 576 * 576, (unsigned short*)o_bf);
        convT_kernel<<<dim3(768 / 32, 768 / 32), 256, 0, stream>>>(w_out + (size_t)l * 768 * 768, wbuf, 768, 768);
        gemm_bt_kernel<64, false, true, false, false><<<dim3(6, 72), 256, 0, stream>>>(
            o_bf, wbuf, nullptr, tok, tok, nullptr, 4608, 768, 768);
        // mlp sub-block
        ln_kernel<__hip_bfloat16><<<4608, 256, 0, stream>>>(tok, ln2_g + l * 768, ln2_b + l * 768, h_bf);
        convT_kernel<<<dim3(3072 / 32, 768 / 32), 256, 0, stream>>>(w1 + (size_t)l * 768 * 3072, wbuf, 768, 3072);
        gemm_bt_kernel<128, true, false, true, true><<<dim3(24, 36), 256, 0, stream>>>(
            h_bf, wbuf, b1 + l * 3072, nullptr, nullptr, hid_bf, 4608, 3072, 768);
        convT_kernel<<<dim3(768 / 32, 3072 / 32), 256, 0, stream>>>(w2 + (size_t)l * 3072 * 768, wbuf, 3072, 768);
        gemm_bt_kernel<64, true, true, false, false><<<dim3(6, 72), 256, 0, stream>>>(
            hid_bf, wbuf, b2 + l * 768, tok, tok, nullptr, 4608, 768, 3072);
    }

    pool_kernel<<<dim3(3, 8), 256, 0, stream>>>(tok, pooled);
    ln_kernel<float><<<8, 256, 0, stream>>>(pooled, lnh_g, lnh_b, pooledln);
    head_kernel<<<dim3(4, 8), 256, 0, stream>>>(pooledln, w_head, b_head, out);
}